// Round 11
// baseline (189.775 us; speedup 1.0000x reference)
//
#include <hip/hip_runtime.h>
#include <math.h>

// Bit-exact emulation of the numpy-fp32 reference pipeline:
//   OpenBLAS sgemm fp32 Gram (KC=384 chunked, sequential per-accumulator k
//   order, sequential chunk fold) -> ssyevd fp32 replica -> fp32 MLP.
// Rounds 3-10 passed with absmax 0.0 — every fp32 operation ORDER is frozen.
// Round 11: chase & SLASR via SWITCH-FALLTHROUGH dispatch into statically
// named-register bodies — executes ONLY the active range [l, m2) (r10's
// predicated full unroll executed all 9 copies every iteration = the 139us).
#pragma clang fp contract(off)

#define NACC 55         // 10*11/2 packed lower-triangle entries (i, j<=i)
#define KC_DEFAULT 384  // OpenBLAS SGEMM_DEFAULT_Q
#define FOLD_LDS 12288  // 48 KB LDS staging capacity (floats)

// ---------------------------------------------------------------------------
// Gram helpers (unchanged, bit-exact-validated)
// ---------------------------------------------------------------------------
__device__ __forceinline__ void group_load(const float4* __restrict__ xv,
                                           long g, float4* buf) {
#pragma unroll
  for (int t = 0; t < 20; ++t) buf[t] = xv[g * 20 + t];
}

__device__ __forceinline__ void pair_fma_one(const float4 q0, const float4 q1,
                                             const float4 q2, const float4 q3,
                                             const float4 q4, float* acc) {
  float a[10] = {q0.x, q0.y, q0.z, q0.w, q1.x, q1.y, q1.z, q1.w, q2.x, q2.y};
  float b[10] = {q2.z, q2.w, q3.x, q3.y, q3.z, q3.w, q4.x, q4.y, q4.z, q4.w};
  int e = 0;
#pragma unroll
  for (int i = 0; i < 10; ++i)
#pragma unroll
    for (int j = 0; j <= i; ++j) {
      acc[e] = __builtin_fmaf(a[i], a[j], acc[e]);
      acc[e] = __builtin_fmaf(b[i], b[j], acc[e]);
      ++e;
    }
}

__device__ __forceinline__ void group_fma(const float4* buf, float* acc) {
#pragma unroll
  for (int pp = 0; pp < 4; ++pp)
    pair_fma_one(buf[pp * 5 + 0], buf[pp * 5 + 1], buf[pp * 5 + 2],
                 buf[pp * 5 + 3], buf[pp * 5 + 4], acc);
}

__global__ __launch_bounds__(64, 1) void gram32_kernel(
    const float* __restrict__ x, float* __restrict__ partial,
    int nrows, int kc, int nchunks, int prow) {
  int c = blockIdx.x * 64 + threadIdx.x;
  if (c >= nchunks) return;
  long k0 = (long)c * kc;
  long rem = (long)nrows - k0;
  int klen = rem < kc ? (int)rem : kc;

  float acc[NACC];
#pragma unroll
  for (int e = 0; e < NACC; ++e) acc[e] = 0.0f;

  const float4* __restrict__ xv = (const float4*)(x + k0 * 10);
  int npair = klen >> 1;
  int ngrp = npair >> 2;

  float4 bufA[20], bufB[20];

  int g = 0;
  if (ngrp > 0) group_load(xv, 0, bufA);
  while (g < ngrp) {
    if (g + 1 < ngrp) group_load(xv, g + 1, bufB);
    group_fma(bufA, acc);
    ++g;
    if (g >= ngrp) break;
    if (g + 1 < ngrp) group_load(xv, g + 1, bufA);
    group_fma(bufB, acc);
    ++g;
  }
  for (int p = ngrp * 4; p < npair; ++p) {
    float4 v0 = xv[(long)p * 5 + 0];
    float4 v1 = xv[(long)p * 5 + 1];
    float4 v2 = xv[(long)p * 5 + 2];
    float4 v3 = xv[(long)p * 5 + 3];
    float4 v4 = xv[(long)p * 5 + 4];
    pair_fma_one(v0, v1, v2, v3, v4, acc);
  }
  if (klen & 1) {
    const float* row = x + (k0 + klen - 1) * 10;
    float a[10];
#pragma unroll
    for (int i = 0; i < 10; ++i) a[i] = row[i];
    int e = 0;
#pragma unroll
    for (int i = 0; i < 10; ++i)
#pragma unroll
      for (int j = 0; j <= i; ++j) {
        acc[e] = __builtin_fmaf(a[i], a[j], acc[e]);
        ++e;
      }
  }
#pragma unroll
  for (int e = 0; e < NACC; ++e)
    partial[(long)e * prow + c] = acc[e];
}

// ---------------------------------------------------------------------------
// Kernel B: sequential fold (unchanged)
// ---------------------------------------------------------------------------
__global__ __launch_bounds__(256) void fold32_kernel(
    const float* __restrict__ partial, float* __restrict__ G, int nchunks,
    int prow) {
  __shared__ float buf[FOLD_LDS];
  int e = blockIdx.x;
  const float* p = partial + (long)e * prow;

  if (nchunks <= FOLD_LDS) {
    int n4 = nchunks >> 2;
    const float4* p4 = (const float4*)p;
    float4* b4 = (float4*)buf;
    for (int i = threadIdx.x; i < n4; i += 256) b4[i] = p4[i];
    for (int i = (n4 << 2) + threadIdx.x; i < nchunks; i += 256)
      buf[i] = p[i];
    __syncthreads();
    if (threadIdx.x == 0) {
      float s = buf[0];
      int c = 1;
      for (; c + 16 <= nchunks; c += 16) {
        float v[16];
#pragma unroll
        for (int t = 0; t < 16; ++t) v[t] = buf[c + t];
#pragma unroll
        for (int t = 0; t < 16; ++t) s = s + v[t];
      }
      for (; c < nchunks; ++c) s = s + buf[c];
      G[e] = s;
    }
  } else {
    if (threadIdx.x == 0) {
      float s = p[0];
      for (int c = 1; c < nchunks; ++c) s = s + p[c];
      G[e] = s;
    }
  }
}

// ---------------------------------------------------------------------------
// Solver scalar helpers
// ---------------------------------------------------------------------------
__device__ __forceinline__ float s_sign(float a, float b) {
  return copysignf(fabsf(a), b);
}
__device__ __forceinline__ float slapy2(float x, float y) {
  float xa = fabsf(x), ya = fabsf(y);
  float w = fmaxf(xa, ya), z = fminf(xa, ya);
  if (z == 0.0f) return w;
  float t = z / w;
  return w * sqrtf(1.0f + t * t);
}
// Branchless slartg (validated bit-exact rounds 9-10).
__device__ __forceinline__ void slartg(float f, float g, float* c, float* s,
                                       float* r) {
  float d = sqrtf(f * f + g * g);
  float cg = fabsf(f) / d;
  float rg = s_sign(d, f);
  float sg = g / rg;
  bool g0 = (g == 0.0f);
  bool f0 = (f == 0.0f);
  *c = g0 ? 1.0f : (f0 ? 0.0f : cg);
  *s = g0 ? 0.0f : (f0 ? s_sign(1.0f, g) : sg);
  *r = g0 ? f : (f0 ? fabsf(g) : rg);
}
__device__ void slaev2(float a, float b, float c, float* rt1, float* rt2,
                       float* cs1, float* sn1) {
  float sm = a + c, df = a - c;
  float adf = fabsf(df);
  float tb = b + b;
  float ab = fabsf(tb);
  float acmx, acmn;
  if (fabsf(a) > fabsf(c)) { acmx = a; acmn = c; } else { acmx = c; acmn = a; }
  float rt;
  if (adf > ab) { float t = ab / adf; rt = adf * sqrtf(1.0f + t * t); }
  else if (adf < ab) { float t = adf / ab; rt = ab * sqrtf(1.0f + t * t); }
  else rt = ab * sqrtf(2.0f);
  int sgn1;
  if (sm < 0.0f) {
    *rt1 = 0.5f * (sm - rt); sgn1 = -1;
    *rt2 = (acmx / *rt1) * acmn - (b / *rt1) * b;
  } else if (sm > 0.0f) {
    *rt1 = 0.5f * (sm + rt); sgn1 = 1;
    *rt2 = (acmx / *rt1) * acmn - (b / *rt1) * b;
  } else {
    *rt1 = 0.5f * rt; *rt2 = -0.5f * rt; sgn1 = 1;
  }
  int sgn2;
  float cs;
  if (df >= 0.0f) { cs = df + rt; sgn2 = 1; } else { cs = df - rt; sgn2 = -1; }
  float acs = fabsf(cs);
  if (acs > ab) {
    float ct = -tb / cs;
    *sn1 = 1.0f / sqrtf(1.0f + ct * ct);
    *cs1 = ct * (*sn1);
  } else {
    if (ab == 0.0f) { *cs1 = 1.0f; *sn1 = 0.0f; }
    else {
      float tn = -cs / tb;
      *cs1 = 1.0f / sqrtf(1.0f + tn * tn);
      *sn1 = tn * (*cs1);
    }
  }
  if (sgn1 == sgn2) { float tn = *cs1; *cs1 = -(*sn1); *sn1 = tn; }
}

// Named-scalar select macros (runtime-index sites only; static sites use
// register names directly).
#define GETD(i) ((i)==0?d0:(i)==1?d1:(i)==2?d2:(i)==3?d3:(i)==4?d4:(i)==5?d5:(i)==6?d6:(i)==7?d7:(i)==8?d8:d9)
#define PUTD(i,v) do{int _i=(i);float _x=(v);d0=(_i==0)?_x:d0;d1=(_i==1)?_x:d1;d2=(_i==2)?_x:d2;d3=(_i==3)?_x:d3;d4=(_i==4)?_x:d4;d5=(_i==5)?_x:d5;d6=(_i==6)?_x:d6;d7=(_i==7)?_x:d7;d8=(_i==8)?_x:d8;d9=(_i==9)?_x:d9;}while(0)
#define GETE(i) ((i)==0?e0:(i)==1?e1:(i)==2?e2:(i)==3?e3:(i)==4?e4:(i)==5?e5:(i)==6?e6:(i)==7?e7:e8)
#define PUTE(i,v) do{int _i=(i);float _x=(v);e0=(_i==0)?_x:e0;e1=(_i==1)?_x:e1;e2=(_i==2)?_x:e2;e3=(_i==3)?_x:e3;e4=(_i==4)?_x:e4;e5=(_i==5)?_x:e5;e6=(_i==6)?_x:e6;e7=(_i==7)?_x:e7;e8=(_i==8)?_x:e8;}while(0)
#define GETZ(i) ((i)==0?z0:(i)==1?z1:(i)==2?z2:(i)==3?z3:(i)==4?z4:(i)==5?z5:(i)==6?z6:(i)==7?z7:(i)==8?z8:z9)
#define PUTZ(i,v) do{int _i=(i);float _x=(v);z0=(_i==0)?_x:z0;z1=(_i==1)?_x:z1;z2=(_i==2)?_x:z2;z3=(_i==3)?_x:z3;z4=(_i==4)?_x:z4;z5=(_i==5)?_x:z5;z6=(_i==6)?_x:z6;z7=(_i==7)?_x:z7;z8=(_i==8)?_x:z8;z9=(_i==9)?_x:z9;}while(0)

// Chase / SLASR step bodies on literal register names (op order == r10).
#define QL_STEP(I, EI, EIP1, DI, DIP1, WCI, WSI) \
  { float f_ = ss * EI; float bb_ = cc * EI; \
    slartg(g, f_, &cc, &ss, &r2); \
    EIP1 = ((I) != m2 - 1) ? r2 : EIP1; \
    g = DIP1 - p; \
    r2 = (DI - g) * ss + 2.0f * cc * bb_; \
    p = ss * r2; \
    DIP1 = g + p; \
    g = cc * r2 - bb_; \
    WCI = cc; WSI = -ss; }

#define QR_STEP(I, EIM1, EI, DI, DIP1, WCI, WSI) \
  { float f_ = ss * EI; float bb_ = cc * EI; \
    slartg(g, f_, &cc, &ss, &r2); \
    EIM1 = ((I) != m2) ? r2 : EIM1; \
    g = DI - p; \
    r2 = (DIP1 - g) * ss + 2.0f * cc * bb_; \
    p = ss * r2; \
    DI = g + p; \
    g = cc * r2 - bb_; \
    WCI = cc; WSI = ss; }

#define QL_ROT(WCJ, WSJ, ZJ, ZJP1) \
  { float t_ = carry; float zj_ = ZJ; \
    ZJP1 = WCJ * t_ - WSJ * zj_; \
    carry = WSJ * t_ + WCJ * zj_; }

#define QR_ROT(WCJ, WSJ, ZJ, ZJP1) \
  { float t_ = ZJP1; float zj_ = carry; \
    ZJ = WSJ * t_ + WCJ * zj_; \
    carry = WCJ * t_ - WSJ * zj_; }

// ---------------------------------------------------------------------------
// Kernel C: ssyevd fp32 replica + fp32 MLP. One wave.
// ---------------------------------------------------------------------------
__global__ __launch_bounds__(64, 1) void solve_kernel(
    const float* __restrict__ Gp, const float* __restrict__ W1,
    const float* __restrict__ b1, const float* __restrict__ W2,
    const float* __restrict__ b2, float* __restrict__ out) {
  __shared__ float zbuf[10 * 11];
  __shared__ float abuf[10 * 11];
  const int lane = threadIdx.x;
  const int myrow = lane < 10 ? lane : 9;

  float row[10];  // static indices only
#pragma unroll
  for (int c = 0; c < 10; ++c) {
    int rr = myrow >= c ? myrow : c;
    int cc = myrow >= c ? c : myrow;
    row[c] = Gp[rr * (rr + 1) / 2 + cc];
  }

  float d0, d1, d2, d3, d4, d5, d6, d7, d8, d9;
  float e0, e1, e2, e3, e4, e5, e6, e7, e8;
  float tau[9];

  // ---- SSYTD2 (UPLO='L'), row-per-lane A (validated rounds 5-10) ----
#pragma unroll
  for (int i = 0; i < 9; ++i) {
    float v[10];
    {
      float myci = row[i];
#pragma unroll
      for (int k = 0; k < 10; ++k) v[k] = __shfl(myci, k, 64);
    }
    float alpha = v[i + 1];
    float xn2 = 0.0f;
#pragma unroll
    for (int k = i + 2; k < 10; ++k) xn2 = xn2 + v[k] * v[k];
    float xnorm = sqrtf(xn2);
    float taui;
    if (xnorm == 0.0f) {
      taui = 0.0f;
      PUTE(i, alpha);
    } else {
      float beta = -s_sign(slapy2(alpha, xnorm), alpha);
      taui = (beta - alpha) / beta;
      float sc = 1.0f / (alpha - beta);
#pragma unroll
      for (int k = i + 2; k < 10; ++k) v[k] = v[k] * sc;
      if (lane >= i + 2 && lane < 10) row[i] = row[i] * sc;
      if (lane == i) {
#pragma unroll
        for (int c = i + 2; c < 10; ++c) row[c] = row[c] * sc;
      }
      if (lane == i + 1) row[i] = beta;
      if (lane == i) row[i + 1] = beta;
      PUTE(i, beta);
    }
    if (taui != 0.0f) {
      v[i + 1] = 1.0f;
      float vme = (lane == i + 1)
                      ? 1.0f
                      : ((lane >= i + 2 && lane < 10) ? row[i] : 0.0f);
      float s = 0.0f;
#pragma unroll
      for (int c2 = i + 1; c2 < 10; ++c2) s = s + row[c2] * v[c2];
      float pvr = taui * s;
      float pva[10];
#pragma unroll
      for (int k = 0; k < 10; ++k) pva[k] = __shfl(pvr, k, 64);
      float dot = 0.0f;
#pragma unroll
      for (int k = i + 1; k < 10; ++k) dot = dot + pva[k] * v[k];
      float alpha2 = -0.5f * taui * dot;
      pvr = pvr + alpha2 * vme;
#pragma unroll
      for (int k = 0; k < 10; ++k) pva[k] = pva[k] + alpha2 * v[k];
      if (lane >= i + 1 && lane < 10) {
#pragma unroll
        for (int c2 = i + 1; c2 < 10; ++c2)
          row[c2] = row[c2] - (vme * pva[c2] + pvr * v[c2]);
      }
    }
    tau[i] = taui;
    PUTD(i, __shfl(row[i], i, 64));
  }
  PUTD(9, __shfl(row[9], 9, 64));

  // ---- SSTEQR('I') ----
  float z0, z1, z2, z3, z4, z5, z6, z7, z8, z9;  // lane r holds row r
  z0 = (lane == 0) ? 1.0f : 0.0f;
  z1 = (lane == 1) ? 1.0f : 0.0f;
  z2 = (lane == 2) ? 1.0f : 0.0f;
  z3 = (lane == 3) ? 1.0f : 0.0f;
  z4 = (lane == 4) ? 1.0f : 0.0f;
  z5 = (lane == 5) ? 1.0f : 0.0f;
  z6 = (lane == 6) ? 1.0f : 0.0f;
  z7 = (lane == 7) ? 1.0f : 0.0f;
  z8 = (lane == 8) ? 1.0f : 0.0f;
  z9 = (lane == 9) ? 1.0f : 0.0f;

  float wc0, wc1, wc2, wc3, wc4, wc5, wc6, wc7, wc8;
  float ws0, ws1, ws2, ws3, ws4, ws5, ws6, ws7, ws8;
  wc0 = wc1 = wc2 = wc3 = wc4 = wc5 = wc6 = wc7 = wc8 = 0.0f;
  ws0 = ws1 = ws2 = ws3 = ws4 = ws5 = ws6 = ws7 = ws8 = 0.0f;

  const float eps = 5.9604644775390625e-08f;   // 2^-24
  const float eps2 = 3.5527136788005009e-15f;  // 2^-48
  const float safmin = 1.1754943508222875e-38f;
  const int nmaxit = 300;
  int jtot = 0;
  int l1 = 0;

  while (l1 < 10) {
    if (l1 > 0) PUTE(l1 - 1, 0.0f);
    int m = 9;
    {
      bool fnd = false;
#pragma unroll
      for (int mm = 0; mm <= 8; ++mm) {
        float tst = fabsf(GETE(mm));
        bool c1 = (tst == 0.0f);
        bool c2 =
            (tst <= (sqrtf(fabsf(GETD(mm))) * sqrtf(fabsf(GETD(mm + 1)))) *
                        eps);
        bool inr = (mm >= l1);
        bool hit = inr && !fnd && (c1 || c2);
        {
          float oldv = GETE(mm);
          PUTE(mm, (hit && !c1) ? 0.0f : oldv);
        }
        m = hit ? mm : m;
        fnd = fnd || hit;
      }
    }
    int l = l1, lsv = l, lend = m, lendsv = lend;
    l1 = m + 1;
    if (lend == l) continue;
    float anorm = 0.0f;
#pragma unroll
    for (int k = 0; k <= 9; ++k) {
      bool in = (k >= l) && (k <= lend);
      anorm = fmaxf(anorm, in ? fabsf(GETD(k)) : 0.0f);
    }
#pragma unroll
    for (int k = 0; k <= 8; ++k) {
      bool in = (k >= l) && (k < lend);
      anorm = fmaxf(anorm, in ? fabsf(GETE(k)) : 0.0f);
    }
    if (anorm == 0.0f) continue;
    if (fabsf(GETD(lend)) < fabsf(GETD(l))) { lend = lsv; l = lendsv; }

    if (lend > l) {
      // --- QL ---
      for (;;) {
        int m2 = lend;
        if (l != lend) {
          bool fnd = false;
#pragma unroll
          for (int mm = 0; mm <= 8; ++mm) {
            float tst = GETE(mm) * GETE(mm);
            bool c =
                (tst <= (eps2 * fabsf(GETD(mm))) * fabsf(GETD(mm + 1)) +
                            safmin);
            bool inr = (mm >= l) && (mm < lend);
            bool hit = inr && !fnd && c;
            m2 = hit ? mm : m2;
            fnd = fnd || hit;
          }
        }
        if (m2 < lend) PUTE(m2, 0.0f);
        float p = GETD(l);
        if (m2 == l) {
          ++l;
          if (l <= lend) continue;
          break;
        }
        if (m2 == l + 1) {
          float rt1, rt2, cc2, ss2;
          slaev2(p, GETE(l), GETD(l + 1), &rt1, &rt2, &cc2, &ss2);
          float zl = GETZ(l), zl1 = GETZ(l + 1);
          float t = zl1;
          PUTZ(l + 1, cc2 * t - ss2 * zl);
          PUTZ(l, ss2 * t + cc2 * zl);
          PUTD(l, rt1);
          PUTD(l + 1, rt2);
          PUTE(l, 0.0f);
          l += 2;
          if (l <= lend) continue;
          break;
        }
        if (jtot == nmaxit) break;
        ++jtot;
        float g = (GETD(l + 1) - p) / (2.0f * GETE(l));
        float r2 = slapy2(g, 1.0f);
        g = GETD(m2) - p + (GETE(l) / (g + s_sign(r2, g)));
        float ss = 1.0f, cc = 1.0f;
        p = 0.0f;
        // chase i2 = m2-1 downto l: switch-dispatch, executes only range
        {
          float edum = 0.0f;
          switch (m2 - 1) {
            case 8: QL_STEP(8, e8, edum, d8, d9, wc8, ws8); if (l == 8) break; [[fallthrough]];
            case 7: QL_STEP(7, e7, e8, d7, d8, wc7, ws7); if (l == 7) break; [[fallthrough]];
            case 6: QL_STEP(6, e6, e7, d6, d7, wc6, ws6); if (l == 6) break; [[fallthrough]];
            case 5: QL_STEP(5, e5, e6, d5, d6, wc5, ws5); if (l == 5) break; [[fallthrough]];
            case 4: QL_STEP(4, e4, e5, d4, d5, wc4, ws4); if (l == 4) break; [[fallthrough]];
            case 3: QL_STEP(3, e3, e4, d3, d4, wc3, ws3); if (l == 3) break; [[fallthrough]];
            case 2: QL_STEP(2, e2, e3, d2, d3, wc2, ws2); if (l == 2) break; [[fallthrough]];
            case 1: QL_STEP(1, e1, e2, d1, d2, wc1, ws1); if (l == 1) break; [[fallthrough]];
            case 0: QL_STEP(0, e0, e1, d0, d1, wc0, ws0); break;
            default: break;
          }
        }
        // SLASR 'R','V','B': j = m2-1 downto l
        {
          float carry = GETZ(m2);
          switch (m2 - 1) {
            case 8: QL_ROT(wc8, ws8, z8, z9); if (l == 8) break; [[fallthrough]];
            case 7: QL_ROT(wc7, ws7, z7, z8); if (l == 7) break; [[fallthrough]];
            case 6: QL_ROT(wc6, ws6, z6, z7); if (l == 6) break; [[fallthrough]];
            case 5: QL_ROT(wc5, ws5, z5, z6); if (l == 5) break; [[fallthrough]];
            case 4: QL_ROT(wc4, ws4, z4, z5); if (l == 4) break; [[fallthrough]];
            case 3: QL_ROT(wc3, ws3, z3, z4); if (l == 3) break; [[fallthrough]];
            case 2: QL_ROT(wc2, ws2, z2, z3); if (l == 2) break; [[fallthrough]];
            case 1: QL_ROT(wc1, ws1, z1, z2); if (l == 1) break; [[fallthrough]];
            case 0: QL_ROT(wc0, ws0, z0, z1); break;
            default: break;
          }
          PUTZ(l, carry);
        }
        PUTD(l, GETD(l) - p);
        PUTE(l, g);
      }
    } else {
      // --- QR ---
      for (;;) {
        int m2 = lend;
        if (l != lend) {
          bool fnd = false;
#pragma unroll
          for (int mm = 9; mm >= 1; --mm) {
            float tst = GETE(mm - 1) * GETE(mm - 1);
            bool c =
                (tst <= (eps2 * fabsf(GETD(mm))) * fabsf(GETD(mm - 1)) +
                            safmin);
            bool inr = (mm <= l) && (mm >= lend + 1);
            bool hit = inr && !fnd && c;
            m2 = hit ? mm : m2;
            fnd = fnd || hit;
          }
        }
        if (m2 > lend) PUTE(m2 - 1, 0.0f);
        float p = GETD(l);
        if (m2 == l) {
          --l;
          if (l >= lend) continue;
          break;
        }
        if (m2 == l - 1) {
          float rt1, rt2, cc2, ss2;
          slaev2(GETD(l - 1), GETE(l - 1), p, &rt1, &rt2, &cc2, &ss2);
          float zl = GETZ(l), zlm = GETZ(l - 1);
          float t = zl;
          PUTZ(l, cc2 * t - ss2 * zlm);
          PUTZ(l - 1, ss2 * t + cc2 * zlm);
          PUTD(l - 1, rt1);
          PUTD(l, rt2);
          PUTE(l - 1, 0.0f);
          l -= 2;
          if (l >= lend) continue;
          break;
        }
        if (jtot == nmaxit) break;
        ++jtot;
        float g = (GETD(l - 1) - p) / (2.0f * GETE(l - 1));
        float r2 = slapy2(g, 1.0f);
        g = GETD(m2) - p + (GETE(l - 1) / (g + s_sign(r2, g)));
        float ss = 1.0f, cc = 1.0f;
        p = 0.0f;
        // chase i2 = m2 .. l-1: switch-dispatch ascending
        {
          float edum = 0.0f;
          switch (m2) {
            case 0: QR_STEP(0, edum, e0, d0, d1, wc0, ws0); if (l - 1 == 0) break; [[fallthrough]];
            case 1: QR_STEP(1, e0, e1, d1, d2, wc1, ws1); if (l - 1 == 1) break; [[fallthrough]];
            case 2: QR_STEP(2, e1, e2, d2, d3, wc2, ws2); if (l - 1 == 2) break; [[fallthrough]];
            case 3: QR_STEP(3, e2, e3, d3, d4, wc3, ws3); if (l - 1 == 3) break; [[fallthrough]];
            case 4: QR_STEP(4, e3, e4, d4, d5, wc4, ws4); if (l - 1 == 4) break; [[fallthrough]];
            case 5: QR_STEP(5, e4, e5, d5, d6, wc5, ws5); if (l - 1 == 5) break; [[fallthrough]];
            case 6: QR_STEP(6, e5, e6, d6, d7, wc6, ws6); if (l - 1 == 6) break; [[fallthrough]];
            case 7: QR_STEP(7, e6, e7, d7, d8, wc7, ws7); if (l - 1 == 7) break; [[fallthrough]];
            case 8: QR_STEP(8, e7, e8, d8, d9, wc8, ws8); break;
            default: break;
          }
        }
        // SLASR 'R','V','F': j = m2 .. l-1
        {
          float carry = GETZ(m2);
          switch (m2) {
            case 0: QR_ROT(wc0, ws0, z0, z1); if (l - 1 == 0) break; [[fallthrough]];
            case 1: QR_ROT(wc1, ws1, z1, z2); if (l - 1 == 1) break; [[fallthrough]];
            case 2: QR_ROT(wc2, ws2, z2, z3); if (l - 1 == 2) break; [[fallthrough]];
            case 3: QR_ROT(wc3, ws3, z3, z4); if (l - 1 == 3) break; [[fallthrough]];
            case 4: QR_ROT(wc4, ws4, z4, z5); if (l - 1 == 4) break; [[fallthrough]];
            case 5: QR_ROT(wc5, ws5, z5, z6); if (l - 1 == 5) break; [[fallthrough]];
            case 6: QR_ROT(wc6, ws6, z6, z7); if (l - 1 == 6) break; [[fallthrough]];
            case 7: QR_ROT(wc7, ws7, z7, z8); if (l - 1 == 7) break; [[fallthrough]];
            case 8: QR_ROT(wc8, ws8, z8, z9); break;
            default: break;
          }
          PUTZ(l, carry);
        }
        PUTD(l, GETD(l) - p);
        PUTE(l - 1, g);
      }
    }
  }

  // ---- ascending selection sort (validated) ----
#pragma unroll
  for (int ii = 1; ii < 10; ++ii) {
    const int i2 = ii - 1;
    int k2 = i2;
    float pmin = GETD(i2);
#pragma unroll
    for (int j = ii; j < 10; ++j) {
      float dj = GETD(j);
      if (dj < pmin) { k2 = j; pmin = dj; }
    }
    if (k2 != i2) {
      PUTD(k2, GETD(i2));
      PUTD(i2, pmin);
      float ti = GETZ(i2);
      float tk = GETZ(k2);
      PUTZ(i2, tk);
      PUTZ(k2, ti);
    }
  }

  // ---- transpose Z via LDS: row-per-lane -> column-per-lane ----
  if (lane < 10) {
#pragma unroll
    for (int c = 0; c < 10; ++c) zbuf[lane * 11 + c] = GETZ(c);
#pragma unroll
    for (int c = 0; c < 10; ++c) abuf[lane * 11 + c] = row[c];
  }
  __syncthreads();
  float zc[10];
#pragma unroll
  for (int r = 0; r < 10; ++r)
    zc[r] = (lane < 10) ? zbuf[r * 11 + lane] : 0.0f;

  // ---- SORM2R: V = H(0)...H(7) * Z ; lane j owns column j ----
#pragma unroll
  for (int i = 8; i >= 0; --i) {
    float taui = tau[i];
    if (taui != 0.0f) {
      float hv[10];
#pragma unroll
      for (int k = 0; k < 10; ++k) hv[k] = abuf[k * 11 + i];
      float w = zc[i + 1];
#pragma unroll
      for (int k2 = i + 2; k2 < 10; ++k2) w = w + hv[k2] * zc[k2];
      w = w * taui;
      zc[i + 1] = zc[i + 1] - w;
#pragma unroll
      for (int k2 = i + 2; k2 < 10; ++k2) zc[k2] = zc[k2] - hv[k2] * w;
    }
  }

  // ---- transpose back via LDS ----
  __syncthreads();
  if (lane < 10) {
#pragma unroll
    for (int r = 0; r < 10; ++r) zbuf[r * 11 + lane] = zc[r];
  }
  __syncthreads();
  float zrow[10];
#pragma unroll
  for (int c = 0; c < 10; ++c)
    zrow[c] = (lane < 10) ? zbuf[lane * 11 + c] : 0.0f;

  // ---- fp32 MLP, numpy op order; lane i computes output row i ----
  if (lane < 10) {
    float o = 0.0f;
#pragma unroll
    for (int j = 0; j < 16; ++j) {
      float acc = 0.0f;
#pragma unroll
      for (int k = 0; k < 10; ++k) acc = acc + zrow[k] * W1[j * 10 + k];
      acc = acc + b1[j];
      float h = fmaxf(acc, 0.0f);
      o = o + h * W2[j];
    }
    o = o + b2[0];
    float sig = 1.0f / (1.0f + expf(-o));
    out[lane] = 0.5f * (sig + 1.0f);
  }
}

// ---------------------------------------------------------------------------
extern "C" void kernel_launch(void* const* d_in, const int* in_sizes, int n_in,
                              void* d_out, int out_size, void* d_ws,
                              size_t ws_size, hipStream_t stream) {
  const float* x = (const float*)d_in[0];
  const float* W1 = (const float*)d_in[1];
  const float* b1 = (const float*)d_in[2];
  const float* W2 = (const float*)d_in[3];
  const float* b2 = (const float*)d_in[4];
  float* out = (float*)d_out;

  int nrows = in_sizes[0] / 10;  // 4,000,000

  int kc = KC_DEFAULT;
  for (;;) {
    long nchunks = ((long)nrows + kc - 1) / kc;
    long prow = (nchunks + 63) & ~63L;
    size_t need = (size_t)NACC * prow * sizeof(float) + 256;
    if (need <= ws_size || kc > nrows) break;
    kc *= 2;
  }
  int nchunks = (int)(((long)nrows + kc - 1) / kc);
  int prow = (int)(((long)nchunks + 63) & ~63L);

  float* partial = (float*)d_ws;
  float* G = partial + (size_t)NACC * prow;

  int grid = (nchunks + 63) / 64;
  gram32_kernel<<<grid, 64, 0, stream>>>(x, partial, nrows, kc, nchunks,
                                         prow);
  fold32_kernel<<<NACC, 256, 0, stream>>>(partial, G, nchunks, prow);
  solve_kernel<<<1, 64, 0, stream>>>(G, W1, b1, W2, b2, out);
}

// Round 12
// 175.391 us; speedup vs baseline: 1.0820x; 1.0820x over previous
//
#include <hip/hip_runtime.h>
#include <math.h>

// Bit-exact emulation of the numpy-fp32 reference pipeline:
//   OpenBLAS sgemm fp32 Gram (KC=384 chunked, sequential per-accumulator k
//   order, sequential chunk fold) -> ssyevd fp32 replica -> fp32 MLP.
// Rounds 3-11 passed with absmax 0.0 — every fp32 operation ORDER is frozen.
// Round 12: base = r8 (best solve, 134us: lane-distributed d/e + ballot
// scans + dynamic loops). Change: SLASR fused INTO the chase step (the Z
// stream and d/e stream are data-disjoint; rotation order identical), which
// deletes wc/ws storage, 2 shuffles/rotation, and the second loop. Tail
// transposes via LDS (r10-validated).
#pragma clang fp contract(off)

#define NACC 55         // 10*11/2 packed lower-triangle entries (i, j<=i)
#define KC_DEFAULT 384  // OpenBLAS SGEMM_DEFAULT_Q
#define FOLD_LDS 12288  // 48 KB LDS staging capacity (floats)

// ---------------------------------------------------------------------------
// Gram helpers (unchanged, bit-exact-validated)
// ---------------------------------------------------------------------------
__device__ __forceinline__ void group_load(const float4* __restrict__ xv,
                                           long g, float4* buf) {
#pragma unroll
  for (int t = 0; t < 20; ++t) buf[t] = xv[g * 20 + t];
}

__device__ __forceinline__ void pair_fma_one(const float4 q0, const float4 q1,
                                             const float4 q2, const float4 q3,
                                             const float4 q4, float* acc) {
  float a[10] = {q0.x, q0.y, q0.z, q0.w, q1.x, q1.y, q1.z, q1.w, q2.x, q2.y};
  float b[10] = {q2.z, q2.w, q3.x, q3.y, q3.z, q3.w, q4.x, q4.y, q4.z, q4.w};
  int e = 0;
#pragma unroll
  for (int i = 0; i < 10; ++i)
#pragma unroll
    for (int j = 0; j <= i; ++j) {
      acc[e] = __builtin_fmaf(a[i], a[j], acc[e]);
      acc[e] = __builtin_fmaf(b[i], b[j], acc[e]);
      ++e;
    }
}

__device__ __forceinline__ void group_fma(const float4* buf, float* acc) {
#pragma unroll
  for (int pp = 0; pp < 4; ++pp)
    pair_fma_one(buf[pp * 5 + 0], buf[pp * 5 + 1], buf[pp * 5 + 2],
                 buf[pp * 5 + 3], buf[pp * 5 + 4], acc);
}

__global__ __launch_bounds__(64, 1) void gram32_kernel(
    const float* __restrict__ x, float* __restrict__ partial,
    int nrows, int kc, int nchunks, int prow) {
  int c = blockIdx.x * 64 + threadIdx.x;
  if (c >= nchunks) return;
  long k0 = (long)c * kc;
  long rem = (long)nrows - k0;
  int klen = rem < kc ? (int)rem : kc;

  float acc[NACC];
#pragma unroll
  for (int e = 0; e < NACC; ++e) acc[e] = 0.0f;

  const float4* __restrict__ xv = (const float4*)(x + k0 * 10);
  int npair = klen >> 1;
  int ngrp = npair >> 2;

  float4 bufA[20], bufB[20];

  int g = 0;
  if (ngrp > 0) group_load(xv, 0, bufA);
  while (g < ngrp) {
    if (g + 1 < ngrp) group_load(xv, g + 1, bufB);
    group_fma(bufA, acc);
    ++g;
    if (g >= ngrp) break;
    if (g + 1 < ngrp) group_load(xv, g + 1, bufA);
    group_fma(bufB, acc);
    ++g;
  }
  for (int p = ngrp * 4; p < npair; ++p) {
    float4 v0 = xv[(long)p * 5 + 0];
    float4 v1 = xv[(long)p * 5 + 1];
    float4 v2 = xv[(long)p * 5 + 2];
    float4 v3 = xv[(long)p * 5 + 3];
    float4 v4 = xv[(long)p * 5 + 4];
    pair_fma_one(v0, v1, v2, v3, v4, acc);
  }
  if (klen & 1) {
    const float* row = x + (k0 + klen - 1) * 10;
    float a[10];
#pragma unroll
    for (int i = 0; i < 10; ++i) a[i] = row[i];
    int e = 0;
#pragma unroll
    for (int i = 0; i < 10; ++i)
#pragma unroll
      for (int j = 0; j <= i; ++j) {
        acc[e] = __builtin_fmaf(a[i], a[j], acc[e]);
        ++e;
      }
  }
#pragma unroll
  for (int e = 0; e < NACC; ++e)
    partial[(long)e * prow + c] = acc[e];
}

// ---------------------------------------------------------------------------
// Kernel B: sequential fold (unchanged)
// ---------------------------------------------------------------------------
__global__ __launch_bounds__(256) void fold32_kernel(
    const float* __restrict__ partial, float* __restrict__ G, int nchunks,
    int prow) {
  __shared__ float buf[FOLD_LDS];
  int e = blockIdx.x;
  const float* p = partial + (long)e * prow;

  if (nchunks <= FOLD_LDS) {
    int n4 = nchunks >> 2;
    const float4* p4 = (const float4*)p;
    float4* b4 = (float4*)buf;
    for (int i = threadIdx.x; i < n4; i += 256) b4[i] = p4[i];
    for (int i = (n4 << 2) + threadIdx.x; i < nchunks; i += 256)
      buf[i] = p[i];
    __syncthreads();
    if (threadIdx.x == 0) {
      float s = buf[0];
      int c = 1;
      for (; c + 16 <= nchunks; c += 16) {
        float v[16];
#pragma unroll
        for (int t = 0; t < 16; ++t) v[t] = buf[c + t];
#pragma unroll
        for (int t = 0; t < 16; ++t) s = s + v[t];
      }
      for (; c < nchunks; ++c) s = s + buf[c];
      G[e] = s;
    }
  } else {
    if (threadIdx.x == 0) {
      float s = p[0];
      for (int c = 1; c < nchunks; ++c) s = s + p[c];
      G[e] = s;
    }
  }
}

// ---------------------------------------------------------------------------
// Solver scalar helpers
// ---------------------------------------------------------------------------
__device__ __forceinline__ float s_sign(float a, float b) {
  return copysignf(fabsf(a), b);
}
__device__ __forceinline__ float slapy2(float x, float y) {
  float xa = fabsf(x), ya = fabsf(y);
  float w = fmaxf(xa, ya), z = fminf(xa, ya);
  if (z == 0.0f) return w;
  float t = z / w;
  return w * sqrtf(1.0f + t * t);
}
// Branchless slartg (validated bit-exact rounds 9-11).
__device__ __forceinline__ void slartg(float f, float g, float* c, float* s,
                                       float* r) {
  float d = sqrtf(f * f + g * g);
  float cg = fabsf(f) / d;
  float rg = s_sign(d, f);
  float sg = g / rg;
  bool g0 = (g == 0.0f);
  bool f0 = (f == 0.0f);
  *c = g0 ? 1.0f : (f0 ? 0.0f : cg);
  *s = g0 ? 0.0f : (f0 ? s_sign(1.0f, g) : sg);
  *r = g0 ? f : (f0 ? fabsf(g) : rg);
}
__device__ void slaev2(float a, float b, float c, float* rt1, float* rt2,
                       float* cs1, float* sn1) {
  float sm = a + c, df = a - c;
  float adf = fabsf(df);
  float tb = b + b;
  float ab = fabsf(tb);
  float acmx, acmn;
  if (fabsf(a) > fabsf(c)) { acmx = a; acmn = c; } else { acmx = c; acmn = a; }
  float rt;
  if (adf > ab) { float t = ab / adf; rt = adf * sqrtf(1.0f + t * t); }
  else if (adf < ab) { float t = adf / ab; rt = ab * sqrtf(1.0f + t * t); }
  else rt = ab * sqrtf(2.0f);
  int sgn1;
  if (sm < 0.0f) {
    *rt1 = 0.5f * (sm - rt); sgn1 = -1;
    *rt2 = (acmx / *rt1) * acmn - (b / *rt1) * b;
  } else if (sm > 0.0f) {
    *rt1 = 0.5f * (sm + rt); sgn1 = 1;
    *rt2 = (acmx / *rt1) * acmn - (b / *rt1) * b;
  } else {
    *rt1 = 0.5f * rt; *rt2 = -0.5f * rt; sgn1 = 1;
  }
  int sgn2;
  float cs;
  if (df >= 0.0f) { cs = df + rt; sgn2 = 1; } else { cs = df - rt; sgn2 = -1; }
  float acs = fabsf(cs);
  if (acs > ab) {
    float ct = -tb / cs;
    *sn1 = 1.0f / sqrtf(1.0f + ct * ct);
    *cs1 = ct * (*sn1);
  } else {
    if (ab == 0.0f) { *cs1 = 1.0f; *sn1 = 0.0f; }
    else {
      float tn = -cs / tb;
      *cs1 = 1.0f / sqrtf(1.0f + tn * tn);
      *sn1 = tn * (*cs1);
    }
  }
  if (sgn1 == sgn2) { float tn = *cs1; *cs1 = -(*sn1); *sn1 = tn; }
}

// Named-scalar select macros (runtime-index sites; static sites fold).
#define GETD(i) ((i)==0?d0:(i)==1?d1:(i)==2?d2:(i)==3?d3:(i)==4?d4:(i)==5?d5:(i)==6?d6:(i)==7?d7:(i)==8?d8:d9)
#define PUTD(i,v) do{int _i=(i);float _x=(v);d0=(_i==0)?_x:d0;d1=(_i==1)?_x:d1;d2=(_i==2)?_x:d2;d3=(_i==3)?_x:d3;d4=(_i==4)?_x:d4;d5=(_i==5)?_x:d5;d6=(_i==6)?_x:d6;d7=(_i==7)?_x:d7;d8=(_i==8)?_x:d8;d9=(_i==9)?_x:d9;}while(0)
#define GETZ(i) ((i)==0?z0:(i)==1?z1:(i)==2?z2:(i)==3?z3:(i)==4?z4:(i)==5?z5:(i)==6?z6:(i)==7?z7:(i)==8?z8:z9)
#define PUTZ(i,v) do{int _i=(i);float _x=(v);z0=(_i==0)?_x:z0;z1=(_i==1)?_x:z1;z2=(_i==2)?_x:z2;z3=(_i==3)?_x:z3;z4=(_i==4)?_x:z4;z5=(_i==5)?_x:z5;z6=(_i==6)?_x:z6;z7=(_i==7)?_x:z7;z8=(_i==8)?_x:z8;z9=(_i==9)?_x:z9;}while(0)

// ---------------------------------------------------------------------------
// Kernel C: ssyevd fp32 replica + fp32 MLP. One wave.
// d/e lane-distributed (dv/ev, lane k owns element k); ballot scans;
// dynamic chase loops with SLASR rotation FUSED into each step.
// Z row-per-lane (named z0..z9). Tail transposes via LDS.
// ---------------------------------------------------------------------------
__global__ __launch_bounds__(64, 1) void solve_kernel(
    const float* __restrict__ Gp, const float* __restrict__ W1,
    const float* __restrict__ b1, const float* __restrict__ W2,
    const float* __restrict__ b2, float* __restrict__ out) {
  __shared__ float zbuf[10 * 11];
  __shared__ float abuf[10 * 11];
  const int lane = threadIdx.x;
  const int myrow = lane < 10 ? lane : 9;

  float row[10];  // static indices only
#pragma unroll
  for (int c = 0; c < 10; ++c) {
    int rr = myrow >= c ? myrow : c;
    int cc = myrow >= c ? c : myrow;
    row[c] = Gp[rr * (rr + 1) / 2 + cc];
  }

  float dv = 0.0f, ev = 0.0f;  // lane k owns d[k] (k<10), e[k] (k<9)
  float tau[9];                // wave-uniform, static indices

  // ---- SSYTD2 (UPLO='L'), row-per-lane A (validated rounds 5-11) ----
#pragma unroll
  for (int i = 0; i < 9; ++i) {
    float v[10];
    {
      float myci = row[i];
#pragma unroll
      for (int k = 0; k < 10; ++k) v[k] = __shfl(myci, k, 64);
    }
    float alpha = v[i + 1];
    float xn2 = 0.0f;
#pragma unroll
    for (int k = i + 2; k < 10; ++k) xn2 = xn2 + v[k] * v[k];
    float xnorm = sqrtf(xn2);
    float taui;
    if (xnorm == 0.0f) {
      taui = 0.0f;
      ev = (lane == i) ? alpha : ev;
    } else {
      float beta = -s_sign(slapy2(alpha, xnorm), alpha);
      taui = (beta - alpha) / beta;
      float sc = 1.0f / (alpha - beta);
#pragma unroll
      for (int k = i + 2; k < 10; ++k) v[k] = v[k] * sc;
      if (lane >= i + 2 && lane < 10) row[i] = row[i] * sc;
      if (lane == i) {
#pragma unroll
        for (int c = i + 2; c < 10; ++c) row[c] = row[c] * sc;
      }
      if (lane == i + 1) row[i] = beta;
      if (lane == i) row[i + 1] = beta;
      ev = (lane == i) ? beta : ev;
    }
    if (taui != 0.0f) {
      v[i + 1] = 1.0f;
      float vme = (lane == i + 1)
                      ? 1.0f
                      : ((lane >= i + 2 && lane < 10) ? row[i] : 0.0f);
      float s = 0.0f;
#pragma unroll
      for (int c2 = i + 1; c2 < 10; ++c2) s = s + row[c2] * v[c2];
      float pvr = taui * s;
      float pva[10];
#pragma unroll
      for (int k = 0; k < 10; ++k) pva[k] = __shfl(pvr, k, 64);
      float dot = 0.0f;
#pragma unroll
      for (int k = i + 1; k < 10; ++k) dot = dot + pva[k] * v[k];
      float alpha2 = -0.5f * taui * dot;
      pvr = pvr + alpha2 * vme;
#pragma unroll
      for (int k = 0; k < 10; ++k) pva[k] = pva[k] + alpha2 * v[k];
      if (lane >= i + 1 && lane < 10) {
#pragma unroll
        for (int c2 = i + 1; c2 < 10; ++c2)
          row[c2] = row[c2] - (vme * pva[c2] + pvr * v[c2]);
      }
    }
    tau[i] = taui;
    {
      float t = __shfl(row[i], i, 64);
      dv = (lane == i) ? t : dv;
    }
  }
  {
    float t = __shfl(row[9], 9, 64);
    dv = (lane == 9) ? t : dv;
  }

  // ---- SSTEQR('I') — lane-distributed d/e, ballot scans, fused SLASR ----
  float z0, z1, z2, z3, z4, z5, z6, z7, z8, z9;  // lane r holds row r
  z0 = (lane == 0) ? 1.0f : 0.0f;
  z1 = (lane == 1) ? 1.0f : 0.0f;
  z2 = (lane == 2) ? 1.0f : 0.0f;
  z3 = (lane == 3) ? 1.0f : 0.0f;
  z4 = (lane == 4) ? 1.0f : 0.0f;
  z5 = (lane == 5) ? 1.0f : 0.0f;
  z6 = (lane == 6) ? 1.0f : 0.0f;
  z7 = (lane == 7) ? 1.0f : 0.0f;
  z8 = (lane == 8) ? 1.0f : 0.0f;
  z9 = (lane == 9) ? 1.0f : 0.0f;

  const float eps = 5.9604644775390625e-08f;   // 2^-24
  const float eps2 = 3.5527136788005009e-15f;  // 2^-48
  const float safmin = 1.1754943508222875e-38f;
  const int nmaxit = 300;
  int jtot = 0;
  int l1 = 0;

  while (l1 < 10) {
    if (l1 > 0) ev = (lane == l1 - 1) ? 0.0f : ev;
    // scan for segment end m: first mm in [l1, 8] with small e[mm]
    int m = 9;
    {
      float dnx = __shfl(dv, (lane + 1) & 63, 64);
      float te = fabsf(ev);
      bool c1 = (te == 0.0f);
      bool c2 = (te <= (sqrtf(fabsf(dv)) * sqrtf(fabsf(dnx))) * eps);
      bool inr = (lane >= l1) && (lane <= 8);
      unsigned long long bal = __ballot(inr && (c1 || c2));
      if (bal) {
        m = __builtin_ctzll(bal);
        ev = ((lane == m) && !c1) ? 0.0f : ev;
      }
    }
    int l = l1, lsv = l, lend = m, lendsv = lend;
    l1 = m + 1;
    if (lend == l) continue;
    // anorm over [l, lend] (exact max selection — order-free)
    float va = (lane >= l && lane <= lend) ? fabsf(dv) : 0.0f;
    float vb = (lane >= l && lane < lend) ? fabsf(ev) : 0.0f;
    float vm = fmaxf(va, vb);
#pragma unroll
    for (int off = 32; off > 0; off >>= 1)
      vm = fmaxf(vm, __shfl_xor(vm, off, 64));
    if (vm == 0.0f) continue;
    {
      float dle = __shfl(dv, lend, 64);
      float dls = __shfl(dv, l, 64);
      if (fabsf(dle) < fabsf(dls)) { lend = lsv; l = lendsv; }
    }

    if (lend > l) {
      // --- QL ---
      for (;;) {
        int m2 = lend;
        if (l != lend) {
          float dnx2 = __shfl(dv, (lane + 1) & 63, 64);
          float t2 = ev * ev;
          bool cnd = (t2 <= (eps2 * fabsf(dv)) * fabsf(dnx2) + safmin);
          bool ir = (lane >= l) && (lane < lend);
          unsigned long long b2 = __ballot(ir && cnd);
          if (b2) m2 = __builtin_ctzll(b2);
        }
        if (m2 < lend) ev = (lane == m2) ? 0.0f : ev;
        float p = __shfl(dv, l, 64);
        if (m2 == l) {
          ++l;
          if (l <= lend) continue;
          break;
        }
        if (m2 == l + 1) {
          float el = __shfl(ev, l, 64);
          float dl1 = __shfl(dv, l + 1, 64);
          float rt1, rt2, cc2, ss2;
          slaev2(p, el, dl1, &rt1, &rt2, &cc2, &ss2);
          float zl = GETZ(l), zl1 = GETZ(l + 1);
          float t = zl1;
          PUTZ(l + 1, cc2 * t - ss2 * zl);
          PUTZ(l, ss2 * t + cc2 * zl);
          dv = (lane == l) ? rt1 : dv;
          dv = (lane == l + 1) ? rt2 : dv;
          ev = (lane == l) ? 0.0f : ev;
          l += 2;
          if (l <= lend) continue;
          break;
        }
        if (jtot == nmaxit) break;
        ++jtot;
        float el = __shfl(ev, l, 64);
        float dl1 = __shfl(dv, l + 1, 64);
        float dm2 = __shfl(dv, m2, 64);
        float g = (dl1 - p) / (2.0f * el);
        float r2 = slapy2(g, 1.0f);
        g = dm2 - p + (el / (g + s_sign(r2, g)));
        float ss = 1.0f, cc = 1.0f;
        p = 0.0f;
        // chase + FUSED SLASR 'R','V','B' (identical op order per stream)
        float carry = GETZ(m2);
#pragma clang loop unroll(disable)
        for (int i2 = m2 - 1; i2 >= l; --i2) {
          float ei2 = __shfl(ev, i2, 64);
          float di2 = __shfl(dv, i2, 64);
          float di21 = __shfl(dv, i2 + 1, 64);
          float zj_ = GETZ(i2);  // pre-pass value (independent, early)
          float f = ss * ei2;
          float bb = cc * ei2;
          slartg(g, f, &cc, &ss, &r2);
          ev = (lane == i2 + 1 && i2 != m2 - 1) ? r2 : ev;
          g = di21 - p;
          r2 = (di2 - g) * ss + 2.0f * cc * bb;
          p = ss * r2;
          dv = (lane == i2 + 1) ? (g + p) : dv;
          g = cc * r2 - bb;
          // rotation j = i2 (cj = cc, sj = -ss), verbatim r8 SLASR body
          {
            float cj = cc, sj = -ss;
            float t_ = carry;
            PUTZ(i2 + 1, cj * t_ - sj * zj_);
            carry = sj * t_ + cj * zj_;
          }
        }
        PUTZ(l, carry);
        {
          float dl0 = __shfl(dv, l, 64);
          dv = (lane == l) ? (dl0 - p) : dv;
        }
        ev = (lane == l) ? g : ev;
      }
    } else {
      // --- QR ---
      for (;;) {
        int m2 = lend;
        if (l != lend) {
          float epv = __shfl(ev, (lane - 1) & 63, 64);
          float dpv = __shfl(dv, (lane - 1) & 63, 64);
          float t2 = epv * epv;
          bool cnd = (t2 <= (eps2 * fabsf(dv)) * fabsf(dpv) + safmin);
          bool ir = (lane >= lend + 1) && (lane <= l);
          unsigned long long b2 = __ballot(ir && cnd);
          if (b2) m2 = 63 - __builtin_clzll(b2);  // descending scan: largest
        }
        if (m2 > lend) ev = (lane == m2 - 1) ? 0.0f : ev;
        float p = __shfl(dv, l, 64);
        if (m2 == l) {
          --l;
          if (l >= lend) continue;
          break;
        }
        if (m2 == l - 1) {
          float dlm = __shfl(dv, l - 1, 64);
          float elm = __shfl(ev, l - 1, 64);
          float rt1, rt2, cc2, ss2;
          slaev2(dlm, elm, p, &rt1, &rt2, &cc2, &ss2);
          float zl = GETZ(l), zlm = GETZ(l - 1);
          float t = zl;
          PUTZ(l, cc2 * t - ss2 * zlm);
          PUTZ(l - 1, ss2 * t + cc2 * zlm);
          dv = (lane == l - 1) ? rt1 : dv;
          dv = (lane == l) ? rt2 : dv;
          ev = (lane == l - 1) ? 0.0f : ev;
          l -= 2;
          if (l >= lend) continue;
          break;
        }
        if (jtot == nmaxit) break;
        ++jtot;
        float elm = __shfl(ev, l - 1, 64);
        float dlm = __shfl(dv, l - 1, 64);
        float dm2 = __shfl(dv, m2, 64);
        float g = (dlm - p) / (2.0f * elm);
        float r2 = slapy2(g, 1.0f);
        g = dm2 - p + (elm / (g + s_sign(r2, g)));
        float ss = 1.0f, cc = 1.0f;
        p = 0.0f;
        // chase + FUSED SLASR 'R','V','F' (identical op order per stream)
        float carry = GETZ(m2);
#pragma clang loop unroll(disable)
        for (int i2 = m2; i2 <= l - 1; ++i2) {
          float ei2 = __shfl(ev, i2, 64);
          float di2 = __shfl(dv, i2, 64);
          float di21 = __shfl(dv, i2 + 1, 64);
          float zjp1 = GETZ(i2 + 1);  // pre-pass value (independent, early)
          float f = ss * ei2;
          float bb = cc * ei2;
          slartg(g, f, &cc, &ss, &r2);
          ev = (lane == i2 - 1 && i2 != m2) ? r2 : ev;
          g = di2 - p;
          r2 = (di21 - g) * ss + 2.0f * cc * bb;
          p = ss * r2;
          dv = (lane == i2) ? (g + p) : dv;
          g = cc * r2 - bb;
          // rotation j = i2 (cj = cc, sj = ss), verbatim r8 SLASR body
          {
            float cj = cc, sj = ss;
            float t_ = zjp1;
            float zj_ = carry;
            PUTZ(i2, sj * t_ + cj * zj_);
            carry = cj * t_ - sj * zj_;
          }
        }
        PUTZ(l, carry);
        {
          float dl0 = __shfl(dv, l, 64);
          dv = (lane == l) ? (dl0 - p) : dv;
        }
        ev = (lane == l - 1) ? g : ev;
      }
    }
  }

  // ---- gather d to wave-uniform named scalars for the sort ----
  float d0 = __shfl(dv, 0, 64), d1 = __shfl(dv, 1, 64);
  float d2 = __shfl(dv, 2, 64), d3 = __shfl(dv, 3, 64);
  float d4 = __shfl(dv, 4, 64), d5 = __shfl(dv, 5, 64);
  float d6 = __shfl(dv, 6, 64), d7 = __shfl(dv, 7, 64);
  float d8 = __shfl(dv, 8, 64), d9 = __shfl(dv, 9, 64);

  // ---- ascending selection sort (validated round 6) ----
#pragma unroll
  for (int ii = 1; ii < 10; ++ii) {
    const int i2 = ii - 1;
    int k2 = i2;
    float pmin = GETD(i2);
#pragma unroll
    for (int j = ii; j < 10; ++j) {
      float dj = GETD(j);
      if (dj < pmin) { k2 = j; pmin = dj; }
    }
    if (k2 != i2) {
      PUTD(k2, GETD(i2));
      PUTD(i2, pmin);
      float ti = GETZ(i2);
      float tk = GETZ(k2);
      PUTZ(i2, tk);
      PUTZ(k2, ti);
    }
  }

  // ---- transpose Z via LDS: row-per-lane -> column-per-lane ----
  if (lane < 10) {
#pragma unroll
    for (int c = 0; c < 10; ++c) zbuf[lane * 11 + c] = GETZ(c);
#pragma unroll
    for (int c = 0; c < 10; ++c) abuf[lane * 11 + c] = row[c];
  }
  __syncthreads();
  float zc[10];
#pragma unroll
  for (int r = 0; r < 10; ++r)
    zc[r] = (lane < 10) ? zbuf[r * 11 + lane] : 0.0f;

  // ---- SORM2R: V = H(0)...H(7) * Z ; lane j owns column j ----
#pragma unroll
  for (int i = 8; i >= 0; --i) {
    float taui = tau[i];
    if (taui != 0.0f) {
      float hv[10];
#pragma unroll
      for (int k = 0; k < 10; ++k) hv[k] = abuf[k * 11 + i];  // broadcast
      float w = zc[i + 1];
#pragma unroll
      for (int k2 = i + 2; k2 < 10; ++k2) w = w + hv[k2] * zc[k2];
      w = w * taui;
      zc[i + 1] = zc[i + 1] - w;
#pragma unroll
      for (int k2 = i + 2; k2 < 10; ++k2) zc[k2] = zc[k2] - hv[k2] * w;
    }
  }

  // ---- transpose back via LDS ----
  __syncthreads();
  if (lane < 10) {
#pragma unroll
    for (int r = 0; r < 10; ++r) zbuf[r * 11 + lane] = zc[r];
  }
  __syncthreads();
  float zrow[10];
#pragma unroll
  for (int c = 0; c < 10; ++c)
    zrow[c] = (lane < 10) ? zbuf[lane * 11 + c] : 0.0f;

  // ---- fp32 MLP, numpy op order; lane i computes output row i ----
  if (lane < 10) {
    float o = 0.0f;
#pragma unroll
    for (int j = 0; j < 16; ++j) {
      float acc = 0.0f;
#pragma unroll
      for (int k = 0; k < 10; ++k) acc = acc + zrow[k] * W1[j * 10 + k];
      acc = acc + b1[j];
      float h = fmaxf(acc, 0.0f);
      o = o + h * W2[j];
    }
    o = o + b2[0];
    float sig = 1.0f / (1.0f + expf(-o));
    out[lane] = 0.5f * (sig + 1.0f);
  }
}

// ---------------------------------------------------------------------------
extern "C" void kernel_launch(void* const* d_in, const int* in_sizes, int n_in,
                              void* d_out, int out_size, void* d_ws,
                              size_t ws_size, hipStream_t stream) {
  const float* x = (const float*)d_in[0];
  const float* W1 = (const float*)d_in[1];
  const float* b1 = (const float*)d_in[2];
  const float* W2 = (const float*)d_in[3];
  const float* b2 = (const float*)d_in[4];
  float* out = (float*)d_out;

  int nrows = in_sizes[0] / 10;  // 4,000,000

  int kc = KC_DEFAULT;
  for (;;) {
    long nchunks = ((long)nrows + kc - 1) / kc;
    long prow = (nchunks + 63) & ~63L;
    size_t need = (size_t)NACC * prow * sizeof(float) + 256;
    if (need <= ws_size || kc > nrows) break;
    kc *= 2;
  }
  int nchunks = (int)(((long)nrows + kc - 1) / kc);
  int prow = (int)(((long)nchunks + 63) & ~63L);

  float* partial = (float*)d_ws;
  float* G = partial + (size_t)NACC * prow;

  int grid = (nchunks + 63) / 64;
  gram32_kernel<<<grid, 64, 0, stream>>>(x, partial, nrows, kc, nchunks,
                                         prow);
  fold32_kernel<<<NACC, 256, 0, stream>>>(partial, G, nchunks, prow);
  solve_kernel<<<1, 64, 0, stream>>>(G, W1, b1, W2, b2, out);
}

// Round 13
// 167.704 us; speedup vs baseline: 1.1316x; 1.0458x over previous
//
#include <hip/hip_runtime.h>
#include <math.h>

// Bit-exact emulation of the numpy-fp32 reference pipeline:
//   OpenBLAS sgemm fp32 Gram (KC=384 chunked, sequential per-accumulator k
//   order, sequential chunk fold) -> ssyevd fp32 replica -> fp32 MLP.
// Rounds 3-12 passed with absmax 0.0 — every fp32 operation ORDER is frozen.
// Round 13: all UNIFORM-index cross-lane reads switched from __shfl
// (ds_bpermute, ~120cy LDS round-trip on a lone wave) to
// __builtin_amdgcn_readlane (v_readlane_b32, ~10cy). Same bits selected ->
// bit-exact. Per-lane-index shuffles (scans, butterfly) stay __shfl.
#pragma clang fp contract(off)

#define NACC 55         // 10*11/2 packed lower-triangle entries (i, j<=i)
#define KC_DEFAULT 384  // OpenBLAS SGEMM_DEFAULT_Q
#define FOLD_LDS 12288  // 48 KB LDS staging capacity (floats)

// ---------------------------------------------------------------------------
// Gram helpers (unchanged, bit-exact-validated)
// ---------------------------------------------------------------------------
__device__ __forceinline__ void group_load(const float4* __restrict__ xv,
                                           long g, float4* buf) {
#pragma unroll
  for (int t = 0; t < 20; ++t) buf[t] = xv[g * 20 + t];
}

__device__ __forceinline__ void pair_fma_one(const float4 q0, const float4 q1,
                                             const float4 q2, const float4 q3,
                                             const float4 q4, float* acc) {
  float a[10] = {q0.x, q0.y, q0.z, q0.w, q1.x, q1.y, q1.z, q1.w, q2.x, q2.y};
  float b[10] = {q2.z, q2.w, q3.x, q3.y, q3.z, q3.w, q4.x, q4.y, q4.z, q4.w};
  int e = 0;
#pragma unroll
  for (int i = 0; i < 10; ++i)
#pragma unroll
    for (int j = 0; j <= i; ++j) {
      acc[e] = __builtin_fmaf(a[i], a[j], acc[e]);
      acc[e] = __builtin_fmaf(b[i], b[j], acc[e]);
      ++e;
    }
}

__device__ __forceinline__ void group_fma(const float4* buf, float* acc) {
#pragma unroll
  for (int pp = 0; pp < 4; ++pp)
    pair_fma_one(buf[pp * 5 + 0], buf[pp * 5 + 1], buf[pp * 5 + 2],
                 buf[pp * 5 + 3], buf[pp * 5 + 4], acc);
}

__global__ __launch_bounds__(64, 1) void gram32_kernel(
    const float* __restrict__ x, float* __restrict__ partial,
    int nrows, int kc, int nchunks, int prow) {
  int c = blockIdx.x * 64 + threadIdx.x;
  if (c >= nchunks) return;
  long k0 = (long)c * kc;
  long rem = (long)nrows - k0;
  int klen = rem < kc ? (int)rem : kc;

  float acc[NACC];
#pragma unroll
  for (int e = 0; e < NACC; ++e) acc[e] = 0.0f;

  const float4* __restrict__ xv = (const float4*)(x + k0 * 10);
  int npair = klen >> 1;
  int ngrp = npair >> 2;

  float4 bufA[20], bufB[20];

  int g = 0;
  if (ngrp > 0) group_load(xv, 0, bufA);
  while (g < ngrp) {
    if (g + 1 < ngrp) group_load(xv, g + 1, bufB);
    group_fma(bufA, acc);
    ++g;
    if (g >= ngrp) break;
    if (g + 1 < ngrp) group_load(xv, g + 1, bufA);
    group_fma(bufB, acc);
    ++g;
  }
  for (int p = ngrp * 4; p < npair; ++p) {
    float4 v0 = xv[(long)p * 5 + 0];
    float4 v1 = xv[(long)p * 5 + 1];
    float4 v2 = xv[(long)p * 5 + 2];
    float4 v3 = xv[(long)p * 5 + 3];
    float4 v4 = xv[(long)p * 5 + 4];
    pair_fma_one(v0, v1, v2, v3, v4, acc);
  }
  if (klen & 1) {
    const float* row = x + (k0 + klen - 1) * 10;
    float a[10];
#pragma unroll
    for (int i = 0; i < 10; ++i) a[i] = row[i];
    int e = 0;
#pragma unroll
    for (int i = 0; i < 10; ++i)
#pragma unroll
      for (int j = 0; j <= i; ++j) {
        acc[e] = __builtin_fmaf(a[i], a[j], acc[e]);
        ++e;
      }
  }
#pragma unroll
  for (int e = 0; e < NACC; ++e)
    partial[(long)e * prow + c] = acc[e];
}

// ---------------------------------------------------------------------------
// Kernel B: sequential fold (unchanged)
// ---------------------------------------------------------------------------
__global__ __launch_bounds__(256) void fold32_kernel(
    const float* __restrict__ partial, float* __restrict__ G, int nchunks,
    int prow) {
  __shared__ float buf[FOLD_LDS];
  int e = blockIdx.x;
  const float* p = partial + (long)e * prow;

  if (nchunks <= FOLD_LDS) {
    int n4 = nchunks >> 2;
    const float4* p4 = (const float4*)p;
    float4* b4 = (float4*)buf;
    for (int i = threadIdx.x; i < n4; i += 256) b4[i] = p4[i];
    for (int i = (n4 << 2) + threadIdx.x; i < nchunks; i += 256)
      buf[i] = p[i];
    __syncthreads();
    if (threadIdx.x == 0) {
      float s = buf[0];
      int c = 1;
      for (; c + 16 <= nchunks; c += 16) {
        float v[16];
#pragma unroll
        for (int t = 0; t < 16; ++t) v[t] = buf[c + t];
#pragma unroll
        for (int t = 0; t < 16; ++t) s = s + v[t];
      }
      for (; c < nchunks; ++c) s = s + buf[c];
      G[e] = s;
    }
  } else {
    if (threadIdx.x == 0) {
      float s = p[0];
      for (int c = 1; c < nchunks; ++c) s = s + p[c];
      G[e] = s;
    }
  }
}

// ---------------------------------------------------------------------------
// Solver scalar helpers
// ---------------------------------------------------------------------------
__device__ __forceinline__ float rdlane(float v, int l) {
  return __int_as_float(__builtin_amdgcn_readlane(__float_as_int(v), l));
}
__device__ __forceinline__ float s_sign(float a, float b) {
  return copysignf(fabsf(a), b);
}
__device__ __forceinline__ float slapy2(float x, float y) {
  float xa = fabsf(x), ya = fabsf(y);
  float w = fmaxf(xa, ya), z = fminf(xa, ya);
  if (z == 0.0f) return w;
  float t = z / w;
  return w * sqrtf(1.0f + t * t);
}
// Branchless slartg (validated bit-exact rounds 9-12).
__device__ __forceinline__ void slartg(float f, float g, float* c, float* s,
                                       float* r) {
  float d = sqrtf(f * f + g * g);
  float cg = fabsf(f) / d;
  float rg = s_sign(d, f);
  float sg = g / rg;
  bool g0 = (g == 0.0f);
  bool f0 = (f == 0.0f);
  *c = g0 ? 1.0f : (f0 ? 0.0f : cg);
  *s = g0 ? 0.0f : (f0 ? s_sign(1.0f, g) : sg);
  *r = g0 ? f : (f0 ? fabsf(g) : rg);
}
__device__ void slaev2(float a, float b, float c, float* rt1, float* rt2,
                       float* cs1, float* sn1) {
  float sm = a + c, df = a - c;
  float adf = fabsf(df);
  float tb = b + b;
  float ab = fabsf(tb);
  float acmx, acmn;
  if (fabsf(a) > fabsf(c)) { acmx = a; acmn = c; } else { acmx = c; acmn = a; }
  float rt;
  if (adf > ab) { float t = ab / adf; rt = adf * sqrtf(1.0f + t * t); }
  else if (adf < ab) { float t = adf / ab; rt = ab * sqrtf(1.0f + t * t); }
  else rt = ab * sqrtf(2.0f);
  int sgn1;
  if (sm < 0.0f) {
    *rt1 = 0.5f * (sm - rt); sgn1 = -1;
    *rt2 = (acmx / *rt1) * acmn - (b / *rt1) * b;
  } else if (sm > 0.0f) {
    *rt1 = 0.5f * (sm + rt); sgn1 = 1;
    *rt2 = (acmx / *rt1) * acmn - (b / *rt1) * b;
  } else {
    *rt1 = 0.5f * rt; *rt2 = -0.5f * rt; sgn1 = 1;
  }
  int sgn2;
  float cs;
  if (df >= 0.0f) { cs = df + rt; sgn2 = 1; } else { cs = df - rt; sgn2 = -1; }
  float acs = fabsf(cs);
  if (acs > ab) {
    float ct = -tb / cs;
    *sn1 = 1.0f / sqrtf(1.0f + ct * ct);
    *cs1 = ct * (*sn1);
  } else {
    if (ab == 0.0f) { *cs1 = 1.0f; *sn1 = 0.0f; }
    else {
      float tn = -cs / tb;
      *cs1 = 1.0f / sqrtf(1.0f + tn * tn);
      *sn1 = tn * (*cs1);
    }
  }
  if (sgn1 == sgn2) { float tn = *cs1; *cs1 = -(*sn1); *sn1 = tn; }
}

// Named-scalar select macros (runtime-index sites; static sites fold).
#define GETD(i) ((i)==0?d0:(i)==1?d1:(i)==2?d2:(i)==3?d3:(i)==4?d4:(i)==5?d5:(i)==6?d6:(i)==7?d7:(i)==8?d8:d9)
#define PUTD(i,v) do{int _i=(i);float _x=(v);d0=(_i==0)?_x:d0;d1=(_i==1)?_x:d1;d2=(_i==2)?_x:d2;d3=(_i==3)?_x:d3;d4=(_i==4)?_x:d4;d5=(_i==5)?_x:d5;d6=(_i==6)?_x:d6;d7=(_i==7)?_x:d7;d8=(_i==8)?_x:d8;d9=(_i==9)?_x:d9;}while(0)
#define GETZ(i) ((i)==0?z0:(i)==1?z1:(i)==2?z2:(i)==3?z3:(i)==4?z4:(i)==5?z5:(i)==6?z6:(i)==7?z7:(i)==8?z8:z9)
#define PUTZ(i,v) do{int _i=(i);float _x=(v);z0=(_i==0)?_x:z0;z1=(_i==1)?_x:z1;z2=(_i==2)?_x:z2;z3=(_i==3)?_x:z3;z4=(_i==4)?_x:z4;z5=(_i==5)?_x:z5;z6=(_i==6)?_x:z6;z7=(_i==7)?_x:z7;z8=(_i==8)?_x:z8;z9=(_i==9)?_x:z9;}while(0)

// ---------------------------------------------------------------------------
// Kernel C: ssyevd fp32 replica + fp32 MLP. One wave.
// d/e lane-distributed (dv/ev); ballot scans; dynamic chase loops with
// fused SLASR; ALL uniform-index cross-lane reads via v_readlane.
// Z row-per-lane (named z0..z9). Tail transposes via LDS.
// ---------------------------------------------------------------------------
__global__ __launch_bounds__(64, 1) void solve_kernel(
    const float* __restrict__ Gp, const float* __restrict__ W1,
    const float* __restrict__ b1, const float* __restrict__ W2,
    const float* __restrict__ b2, float* __restrict__ out) {
  __shared__ float zbuf[10 * 11];
  __shared__ float abuf[10 * 11];
  const int lane = threadIdx.x;
  const int myrow = lane < 10 ? lane : 9;

  float row[10];  // static indices only
#pragma unroll
  for (int c = 0; c < 10; ++c) {
    int rr = myrow >= c ? myrow : c;
    int cc = myrow >= c ? c : myrow;
    row[c] = Gp[rr * (rr + 1) / 2 + cc];
  }

  float dv = 0.0f, ev = 0.0f;  // lane k owns d[k] (k<10), e[k] (k<9)
  float tau[9];                // wave-uniform, static indices

  // ---- SSYTD2 (UPLO='L'), row-per-lane A (validated rounds 5-12) ----
#pragma unroll
  for (int i = 0; i < 9; ++i) {
    float v[10];
    {
      float myci = row[i];
#pragma unroll
      for (int k = 0; k < 10; ++k) v[k] = rdlane(myci, k);
    }
    float alpha = v[i + 1];
    float xn2 = 0.0f;
#pragma unroll
    for (int k = i + 2; k < 10; ++k) xn2 = xn2 + v[k] * v[k];
    float xnorm = sqrtf(xn2);
    float taui;
    if (xnorm == 0.0f) {
      taui = 0.0f;
      ev = (lane == i) ? alpha : ev;
    } else {
      float beta = -s_sign(slapy2(alpha, xnorm), alpha);
      taui = (beta - alpha) / beta;
      float sc = 1.0f / (alpha - beta);
#pragma unroll
      for (int k = i + 2; k < 10; ++k) v[k] = v[k] * sc;
      if (lane >= i + 2 && lane < 10) row[i] = row[i] * sc;
      if (lane == i) {
#pragma unroll
        for (int c = i + 2; c < 10; ++c) row[c] = row[c] * sc;
      }
      if (lane == i + 1) row[i] = beta;
      if (lane == i) row[i + 1] = beta;
      ev = (lane == i) ? beta : ev;
    }
    if (taui != 0.0f) {
      v[i + 1] = 1.0f;
      float vme = (lane == i + 1)
                      ? 1.0f
                      : ((lane >= i + 2 && lane < 10) ? row[i] : 0.0f);
      float s = 0.0f;
#pragma unroll
      for (int c2 = i + 1; c2 < 10; ++c2) s = s + row[c2] * v[c2];
      float pvr = taui * s;
      float pva[10];
#pragma unroll
      for (int k = 0; k < 10; ++k) pva[k] = rdlane(pvr, k);
      float dot = 0.0f;
#pragma unroll
      for (int k = i + 1; k < 10; ++k) dot = dot + pva[k] * v[k];
      float alpha2 = -0.5f * taui * dot;
      pvr = pvr + alpha2 * vme;
#pragma unroll
      for (int k = 0; k < 10; ++k) pva[k] = pva[k] + alpha2 * v[k];
      if (lane >= i + 1 && lane < 10) {
#pragma unroll
        for (int c2 = i + 1; c2 < 10; ++c2)
          row[c2] = row[c2] - (vme * pva[c2] + pvr * v[c2]);
      }
    }
    tau[i] = taui;
    {
      float t = rdlane(row[i], i);
      dv = (lane == i) ? t : dv;
    }
  }
  {
    float t = rdlane(row[9], 9);
    dv = (lane == 9) ? t : dv;
  }

  // ---- SSTEQR('I') — lane-distributed d/e, ballot scans, fused SLASR ----
  float z0, z1, z2, z3, z4, z5, z6, z7, z8, z9;  // lane r holds row r
  z0 = (lane == 0) ? 1.0f : 0.0f;
  z1 = (lane == 1) ? 1.0f : 0.0f;
  z2 = (lane == 2) ? 1.0f : 0.0f;
  z3 = (lane == 3) ? 1.0f : 0.0f;
  z4 = (lane == 4) ? 1.0f : 0.0f;
  z5 = (lane == 5) ? 1.0f : 0.0f;
  z6 = (lane == 6) ? 1.0f : 0.0f;
  z7 = (lane == 7) ? 1.0f : 0.0f;
  z8 = (lane == 8) ? 1.0f : 0.0f;
  z9 = (lane == 9) ? 1.0f : 0.0f;

  const float eps = 5.9604644775390625e-08f;   // 2^-24
  const float eps2 = 3.5527136788005009e-15f;  // 2^-48
  const float safmin = 1.1754943508222875e-38f;
  const int nmaxit = 300;
  int jtot = 0;
  int l1 = 0;

  while (l1 < 10) {
    if (l1 > 0) ev = (lane == l1 - 1) ? 0.0f : ev;
    // scan for segment end m: first mm in [l1, 8] with small e[mm]
    int m = 9;
    {
      float dnx = __shfl(dv, (lane + 1) & 63, 64);  // per-lane: keep shfl
      float te = fabsf(ev);
      bool c1 = (te == 0.0f);
      bool c2 = (te <= (sqrtf(fabsf(dv)) * sqrtf(fabsf(dnx))) * eps);
      bool inr = (lane >= l1) && (lane <= 8);
      unsigned long long bal = __ballot(inr && (c1 || c2));
      if (bal) {
        m = __builtin_ctzll(bal);
        ev = ((lane == m) && !c1) ? 0.0f : ev;
      }
    }
    int l = l1, lsv = l, lend = m, lendsv = lend;
    l1 = m + 1;
    if (lend == l) continue;
    // anorm over [l, lend] (exact max selection — order-free)
    float va = (lane >= l && lane <= lend) ? fabsf(dv) : 0.0f;
    float vb = (lane >= l && lane < lend) ? fabsf(ev) : 0.0f;
    float vm = fmaxf(va, vb);
#pragma unroll
    for (int off = 32; off > 0; off >>= 1)
      vm = fmaxf(vm, __shfl_xor(vm, off, 64));  // per-lane butterfly: keep
    if (vm == 0.0f) continue;
    {
      float dle = rdlane(dv, lend);
      float dls = rdlane(dv, l);
      if (fabsf(dle) < fabsf(dls)) { lend = lsv; l = lendsv; }
    }

    if (lend > l) {
      // --- QL ---
      for (;;) {
        int m2 = lend;
        if (l != lend) {
          float dnx2 = __shfl(dv, (lane + 1) & 63, 64);  // per-lane: keep
          float t2 = ev * ev;
          bool cnd = (t2 <= (eps2 * fabsf(dv)) * fabsf(dnx2) + safmin);
          bool ir = (lane >= l) && (lane < lend);
          unsigned long long b2 = __ballot(ir && cnd);
          if (b2) m2 = __builtin_ctzll(b2);
        }
        if (m2 < lend) ev = (lane == m2) ? 0.0f : ev;
        float p = rdlane(dv, l);
        if (m2 == l) {
          ++l;
          if (l <= lend) continue;
          break;
        }
        if (m2 == l + 1) {
          float el = rdlane(ev, l);
          float dl1 = rdlane(dv, l + 1);
          float rt1, rt2, cc2, ss2;
          slaev2(p, el, dl1, &rt1, &rt2, &cc2, &ss2);
          float zl = GETZ(l), zl1 = GETZ(l + 1);
          float t = zl1;
          PUTZ(l + 1, cc2 * t - ss2 * zl);
          PUTZ(l, ss2 * t + cc2 * zl);
          dv = (lane == l) ? rt1 : dv;
          dv = (lane == l + 1) ? rt2 : dv;
          ev = (lane == l) ? 0.0f : ev;
          l += 2;
          if (l <= lend) continue;
          break;
        }
        if (jtot == nmaxit) break;
        ++jtot;
        float el = rdlane(ev, l);
        float dl1 = rdlane(dv, l + 1);
        float dm2 = rdlane(dv, m2);
        float g = (dl1 - p) / (2.0f * el);
        float r2 = slapy2(g, 1.0f);
        g = dm2 - p + (el / (g + s_sign(r2, g)));
        float ss = 1.0f, cc = 1.0f;
        p = 0.0f;
        // chase + FUSED SLASR 'R','V','B' (identical op order per stream)
        float carry = GETZ(m2);
#pragma clang loop unroll(disable)
        for (int i2 = m2 - 1; i2 >= l; --i2) {
          float ei2 = rdlane(ev, i2);
          float di2 = rdlane(dv, i2);
          float di21 = rdlane(dv, i2 + 1);
          float zj_ = GETZ(i2);  // pre-pass value (independent, early)
          float f = ss * ei2;
          float bb = cc * ei2;
          slartg(g, f, &cc, &ss, &r2);
          ev = (lane == i2 + 1 && i2 != m2 - 1) ? r2 : ev;
          g = di21 - p;
          r2 = (di2 - g) * ss + 2.0f * cc * bb;
          p = ss * r2;
          dv = (lane == i2 + 1) ? (g + p) : dv;
          g = cc * r2 - bb;
          // rotation j = i2 (cj = cc, sj = -ss), verbatim r8 SLASR body
          {
            float cj = cc, sj = -ss;
            float t_ = carry;
            PUTZ(i2 + 1, cj * t_ - sj * zj_);
            carry = sj * t_ + cj * zj_;
          }
        }
        PUTZ(l, carry);
        {
          float dl0 = rdlane(dv, l);
          dv = (lane == l) ? (dl0 - p) : dv;
        }
        ev = (lane == l) ? g : ev;
      }
    } else {
      // --- QR ---
      for (;;) {
        int m2 = lend;
        if (l != lend) {
          float epv = __shfl(ev, (lane - 1) & 63, 64);  // per-lane: keep
          float dpv = __shfl(dv, (lane - 1) & 63, 64);
          float t2 = epv * epv;
          bool cnd = (t2 <= (eps2 * fabsf(dv)) * fabsf(dpv) + safmin);
          bool ir = (lane >= lend + 1) && (lane <= l);
          unsigned long long b2 = __ballot(ir && cnd);
          if (b2) m2 = 63 - __builtin_clzll(b2);  // descending scan: largest
        }
        if (m2 > lend) ev = (lane == m2 - 1) ? 0.0f : ev;
        float p = rdlane(dv, l);
        if (m2 == l) {
          --l;
          if (l >= lend) continue;
          break;
        }
        if (m2 == l - 1) {
          float dlm = rdlane(dv, l - 1);
          float elm = rdlane(ev, l - 1);
          float rt1, rt2, cc2, ss2;
          slaev2(dlm, elm, p, &rt1, &rt2, &cc2, &ss2);
          float zl = GETZ(l), zlm = GETZ(l - 1);
          float t = zl;
          PUTZ(l, cc2 * t - ss2 * zlm);
          PUTZ(l - 1, ss2 * t + cc2 * zlm);
          dv = (lane == l - 1) ? rt1 : dv;
          dv = (lane == l) ? rt2 : dv;
          ev = (lane == l - 1) ? 0.0f : ev;
          l -= 2;
          if (l >= lend) continue;
          break;
        }
        if (jtot == nmaxit) break;
        ++jtot;
        float elm = rdlane(ev, l - 1);
        float dlm = rdlane(dv, l - 1);
        float dm2 = rdlane(dv, m2);
        float g = (dlm - p) / (2.0f * elm);
        float r2 = slapy2(g, 1.0f);
        g = dm2 - p + (elm / (g + s_sign(r2, g)));
        float ss = 1.0f, cc = 1.0f;
        p = 0.0f;
        // chase + FUSED SLASR 'R','V','F' (identical op order per stream)
        float carry = GETZ(m2);
#pragma clang loop unroll(disable)
        for (int i2 = m2; i2 <= l - 1; ++i2) {
          float ei2 = rdlane(ev, i2);
          float di2 = rdlane(dv, i2);
          float di21 = rdlane(dv, i2 + 1);
          float zjp1 = GETZ(i2 + 1);  // pre-pass value (independent, early)
          float f = ss * ei2;
          float bb = cc * ei2;
          slartg(g, f, &cc, &ss, &r2);
          ev = (lane == i2 - 1 && i2 != m2) ? r2 : ev;
          g = di2 - p;
          r2 = (di21 - g) * ss + 2.0f * cc * bb;
          p = ss * r2;
          dv = (lane == i2) ? (g + p) : dv;
          g = cc * r2 - bb;
          // rotation j = i2 (cj = cc, sj = ss), verbatim r8 SLASR body
          {
            float cj = cc, sj = ss;
            float t_ = zjp1;
            float zj_ = carry;
            PUTZ(i2, sj * t_ + cj * zj_);
            carry = cj * t_ - sj * zj_;
          }
        }
        PUTZ(l, carry);
        {
          float dl0 = rdlane(dv, l);
          dv = (lane == l) ? (dl0 - p) : dv;
        }
        ev = (lane == l - 1) ? g : ev;
      }
    }
  }

  // ---- gather d to wave-uniform named scalars for the sort ----
  float d0 = rdlane(dv, 0), d1 = rdlane(dv, 1);
  float d2 = rdlane(dv, 2), d3 = rdlane(dv, 3);
  float d4 = rdlane(dv, 4), d5 = rdlane(dv, 5);
  float d6 = rdlane(dv, 6), d7 = rdlane(dv, 7);
  float d8 = rdlane(dv, 8), d9 = rdlane(dv, 9);

  // ---- ascending selection sort (validated round 6) ----
#pragma unroll
  for (int ii = 1; ii < 10; ++ii) {
    const int i2 = ii - 1;
    int k2 = i2;
    float pmin = GETD(i2);
#pragma unroll
    for (int j = ii; j < 10; ++j) {
      float dj = GETD(j);
      if (dj < pmin) { k2 = j; pmin = dj; }
    }
    if (k2 != i2) {
      PUTD(k2, GETD(i2));
      PUTD(i2, pmin);
      float ti = GETZ(i2);
      float tk = GETZ(k2);
      PUTZ(i2, tk);
      PUTZ(k2, ti);
    }
  }

  // ---- transpose Z via LDS: row-per-lane -> column-per-lane ----
  if (lane < 10) {
#pragma unroll
    for (int c = 0; c < 10; ++c) zbuf[lane * 11 + c] = GETZ(c);
#pragma unroll
    for (int c = 0; c < 10; ++c) abuf[lane * 11 + c] = row[c];
  }
  __syncthreads();
  float zc[10];
#pragma unroll
  for (int r = 0; r < 10; ++r)
    zc[r] = (lane < 10) ? zbuf[r * 11 + lane] : 0.0f;

  // ---- SORM2R: V = H(0)...H(7) * Z ; lane j owns column j ----
#pragma unroll
  for (int i = 8; i >= 0; --i) {
    float taui = tau[i];
    if (taui != 0.0f) {
      float hv[10];
#pragma unroll
      for (int k = 0; k < 10; ++k) hv[k] = abuf[k * 11 + i];  // broadcast
      float w = zc[i + 1];
#pragma unroll
      for (int k2 = i + 2; k2 < 10; ++k2) w = w + hv[k2] * zc[k2];
      w = w * taui;
      zc[i + 1] = zc[i + 1] - w;
#pragma unroll
      for (int k2 = i + 2; k2 < 10; ++k2) zc[k2] = zc[k2] - hv[k2] * w;
    }
  }

  // ---- transpose back via LDS ----
  __syncthreads();
  if (lane < 10) {
#pragma unroll
    for (int r = 0; r < 10; ++r) zbuf[r * 11 + lane] = zc[r];
  }
  __syncthreads();
  float zrow[10];
#pragma unroll
  for (int c = 0; c < 10; ++c)
    zrow[c] = (lane < 10) ? zbuf[lane * 11 + c] : 0.0f;

  // ---- fp32 MLP, numpy op order; lane i computes output row i ----
  if (lane < 10) {
    float o = 0.0f;
#pragma unroll
    for (int j = 0; j < 16; ++j) {
      float acc = 0.0f;
#pragma unroll
      for (int k = 0; k < 10; ++k) acc = acc + zrow[k] * W1[j * 10 + k];
      acc = acc + b1[j];
      float h = fmaxf(acc, 0.0f);
      o = o + h * W2[j];
    }
    o = o + b2[0];
    float sig = 1.0f / (1.0f + expf(-o));
    out[lane] = 0.5f * (sig + 1.0f);
  }
}

// ---------------------------------------------------------------------------
extern "C" void kernel_launch(void* const* d_in, const int* in_sizes, int n_in,
                              void* d_out, int out_size, void* d_ws,
                              size_t ws_size, hipStream_t stream) {
  const float* x = (const float*)d_in[0];
  const float* W1 = (const float*)d_in[1];
  const float* b1 = (const float*)d_in[2];
  const float* W2 = (const float*)d_in[3];
  const float* b2 = (const float*)d_in[4];
  float* out = (float*)d_out;

  int nrows = in_sizes[0] / 10;  // 4,000,000

  int kc = KC_DEFAULT;
  for (;;) {
    long nchunks = ((long)nrows + kc - 1) / kc;
    long prow = (nchunks + 63) & ~63L;
    size_t need = (size_t)NACC * prow * sizeof(float) + 256;
    if (need <= ws_size || kc > nrows) break;
    kc *= 2;
  }
  int nchunks = (int)(((long)nrows + kc - 1) / kc);
  int prow = (int)(((long)nchunks + 63) & ~63L);

  float* partial = (float*)d_ws;
  float* G = partial + (size_t)NACC * prow;

  int grid = (nchunks + 63) / 64;
  gram32_kernel<<<grid, 64, 0, stream>>>(x, partial, nrows, kc, nchunks,
                                         prow);
  fold32_kernel<<<NACC, 256, 0, stream>>>(partial, G, nchunks, prow);
  solve_kernel<<<1, 64, 0, stream>>>(G, W1, b1, W2, b2, out);
}